// Round 14
// baseline (73.043 us; speedup 1.0000x reference)
//
#include <hip/hip_runtime.h>
#include <hip/hip_bf16.h>
#include <math.h>

#define EPSF 1e-8f

constexpr int N_OBJ  = 8192;
constexpr int M_SR   = 4096;
constexpr int N_FACE = 2048;

constexpr int PPB  = 16;             // points per block
constexpr int NBLK = N_OBJ / PPB;    // 512
constexpr int FT   = 256;            // faces per LDS tile
constexpr int NT   = N_FACE / FT;    // 8

// ws: pensum[512] floats (fully overwritten each call)

__global__ __launch_bounds__(256) void fused(
    const float* __restrict__ obj, const float* __restrict__ srp,
    const float* __restrict__ verts, const int* __restrict__ faces,
    const float* __restrict__ fnorm, float* __restrict__ out,
    float* __restrict__ pensum)
{
    __shared__ float4 fq[2][4][FT];    // 32 KB, component-split (stride 16B: conflict-free)
    __shared__ float  ptd[PPB][9];     // point records (padded rows)
    __shared__ int    scnt[16][17];    // per-sub hit counts

    const int tid   = threadIdx.x;
    const int pbase = blockIdx.x * PPB;

    // ---- face tile staging (one face per thread, component-split writes) ----
    auto stage = [&](int buf, int t8) {
        const int f  = t8 * FT + tid;
        const int i0 = faces[3 * f + 0], i1 = faces[3 * f + 1], i2 = faces[3 * f + 2];
        const float ax = verts[3 * i0 + 0], ay = verts[3 * i0 + 1], az = verts[3 * i0 + 2];
        const float bx = verts[3 * i1 + 0], by = verts[3 * i1 + 1], bz = verts[3 * i1 + 2];
        const float cx = verts[3 * i2 + 0], cy = verts[3 * i2 + 1], cz = verts[3 * i2 + 2];
        const float fx = fnorm[3 * f + 0], fy = fnorm[3 * f + 1], fz = fnorm[3 * f + 2];
        const float nf = fx * ax + fy * ay + fz * az;

        const float e0x = bx - ax, e0y = by - ay, e0z = bz - az;
        const float g0x = fy * e0z - fz * e0y, g0y = fz * e0x - fx * e0z, g0z = fx * e0y - fy * e0x;
        const float h0  = g0x * ax + g0y * ay + g0z * az;
        const float e1x = cx - bx, e1y = cy - by, e1z = cz - bz;
        const float g1x = fy * e1z - fz * e1y, g1y = fz * e1x - fx * e1z, g1z = fx * e1y - fy * e1x;
        const float h1  = g1x * bx + g1y * by + g1z * bz;
        const float e2x = ax - cx, e2y = ay - cy, e2z = az - cz;
        const float g2x = fy * e2z - fz * e2y, g2y = fz * e2x - fx * e2z, g2z = fx * e2y - fy * e2x;
        const float h2  = g2x * cx + g2y * cy + g2z * cz;

        fq[buf][0][tid] = make_float4(fx, fy, fz, nf);
        fq[buf][1][tid] = make_float4(g0x, g0y, g0z, h0);
        fq[buf][2][tid] = make_float4(g1x, g1y, g1z, h1);
        fq[buf][3][tid] = make_float4(g2x, g2y, g2z, h2);
    };

    stage(0, 0);    // overlap tile-0 staging with phase A

    // ========== Phase A: NN — sub owns contiguous 256 sr pts, 3 loads / 4 pts ==========
    {
        const int ptA  = tid >> 4;
        const int subA = tid & 15;
        const int p    = pbase + ptA;
        const float ox = obj[3 * p], oy = obj[3 * p + 1], oz = obj[3 * p + 2];

        float best = 3.4e38f;
        int   bi   = 0;
        const float* __restrict__ sp0 = srp + subA * 768;   // 256 pts * 3 floats
#pragma unroll 4
        for (int j = 0; j < 64; ++j) {
            const float* sp = sp0 + j * 12;
            float4 f0 = *(const float4*)(sp + 0);
            float4 f1 = *(const float4*)(sp + 4);
            float4 f2 = *(const float4*)(sp + 8);
            const int ib = subA * 256 + j * 4;
            {   float dx = ox - f0.x, dy = oy - f0.y, dz = oz - f0.z;
                float d2 = dx * dx + dy * dy + dz * dz;
                if (d2 < best) { best = d2; bi = ib + 0; } }
            {   float dx = ox - f0.w, dy = oy - f1.x, dz = oz - f1.y;
                float d2 = dx * dx + dy * dy + dz * dz;
                if (d2 < best) { best = d2; bi = ib + 1; } }
            {   float dx = ox - f1.z, dy = oy - f1.w, dz = oz - f2.x;
                float d2 = dx * dx + dy * dy + dz * dz;
                if (d2 < best) { best = d2; bi = ib + 2; } }
            {   float dx = ox - f2.y, dy = oy - f2.z, dz = oz - f2.w;
                float d2 = dx * dx + dy * dy + dz * dz;
                if (d2 < best) { best = d2; bi = ib + 3; } }
        }
        // reduce across the 16 subs (same wave); subs are index-ordered so
        // (strict-less, lower-index-wins) == global first-min
#pragma unroll
        for (int off = 1; off < 16; off <<= 1) {
            float od = __shfl_xor(best, off);
            int   oi = __shfl_xor(bi, off);
            if (od < best || (od == best && oi < bi)) { best = od; bi = oi; }
        }
        if (subA == 0) {
            float dx = srp[3 * bi] - ox, dy = srp[3 * bi + 1] - oy, dz = srp[3 * bi + 2] - oz;
            ptd[ptA][0] = ox; ptd[ptA][1] = oy; ptd[ptA][2] = oz;
            ptd[ptA][3] = dx; ptd[ptA][4] = dy; ptd[ptA][5] = dz;
            ptd[ptA][6] = best;
            out[1 + p] = 2.0f / (1.0f + expf(100.0f * sqrtf(best + EPSF)));
        }
    }
    __syncthreads();   // ptd ready, tile-0 staged

    // ========== Phase B: ray-triangle parity over 8 dbuf tiles ==========
    const int subB = tid >> 4;    // face sub-slice 0..15
    const int ptB  = tid & 15;    // point 0..15
    const float ox = ptd[ptB][0], oy = ptd[ptB][1], oz = ptd[ptB][2];
    const float dx = ptd[ptB][3], dy = ptd[ptB][4], dz = ptd[ptB][5];

    int cnt = 0;
    for (int t8 = 0; t8 < NT; ++t8) {
        if (t8 < NT - 1) stage((t8 + 1) & 1, t8 + 1);
        const int buf = t8 & 1;
#pragma unroll 4
        for (int k = 0; k < 16; ++k) {
            const int fl = k * 16 + subB;          // 16-lane broadcast per read
            float4 q0 = fq[buf][0][fl];
            float den = q0.x * dx + q0.y * dy + q0.z * dz;
            float num = q0.w - (q0.x * ox + q0.y * oy + q0.z * oz);
            float Px  = den * ox + num * dx;
            float Py  = den * oy + num * dy;
            float Pz  = den * oz + num * dz;
            bool pos = den >= 0.0f;

            float4 q1 = fq[buf][1][fl];
            bool ok0 = ((q1.x * Px + q1.y * Py + q1.z * Pz - den * q1.w) >= 0.0f) == pos;
            float4 q2 = fq[buf][2][fl];
            bool ok1 = ((q2.x * Px + q2.y * Py + q2.z * Pz - den * q2.w) >= 0.0f) == pos;
            float4 q3 = fq[buf][3][fl];
            bool ok2 = ((q3.x * Px + q3.y * Py + q3.z * Pz - den * q3.w) >= 0.0f) == pos;

            bool tok = (num >= 0.0f) == pos;
            bool aok = fabsf(den) >= EPSF;
            cnt += (ok0 & ok1 & ok2 & tok & aok) ? 1 : 0;
        }
        __syncthreads();   // next buffer staged; current reads done
    }

    // ========== Phase C: in-block parity + pen partial ==========
    scnt[subB][ptB] = cnt;
    __syncthreads();
    float s = 0.0f;
    if (tid < PPB) {
        int tot = 0;
#pragma unroll
        for (int sb = 0; sb < 16; ++sb) tot += scnt[sb][tid];
        s = (tot & 1) ? ptd[tid][6] : 0.0f;
    }
#pragma unroll
    for (int off = 1; off < 16; off <<= 1) s += __shfl_xor(s, off);
    if (tid == 0) pensum[blockIdx.x] = s;
}

// ================= FIN: sum 512 partials -> sqrt -> out[0] =================
__global__ __launch_bounds__(64) void fin(
    const float* __restrict__ pensum, float* __restrict__ out)
{
    const int l = threadIdx.x;
    const float4* __restrict__ p4 = (const float4*)pensum;   // 128 float4
    float4 a = p4[2 * l], b = p4[2 * l + 1];
    float s = a.x + a.y + a.z + a.w + b.x + b.y + b.z + b.w;
#pragma unroll
    for (int off = 1; off < 64; off <<= 1) s += __shfl_xor(s, off);
    if (l == 0) out[0] = sqrtf(s);
}

extern "C" void kernel_launch(void* const* d_in, const int* in_sizes, int n_in,
                              void* d_out, int out_size, void* d_ws, size_t ws_size,
                              hipStream_t stream)
{
    const float* obj   = (const float*)d_in[0];
    const float* srp   = (const float*)d_in[1];
    const float* verts = (const float*)d_in[2];
    const int*   faces = (const int*)d_in[3];
    const float* fnorm = (const float*)d_in[4];
    float*       out   = (float*)d_out;
    float*       pensum = (float*)d_ws;

    fused<<<NBLK, 256, 0, stream>>>(obj, srp, verts, faces, fnorm, out, pensum);
    fin<<<1, 64, 0, stream>>>(pensum, out);
}

// Round 16
// 40.219 us; speedup vs baseline: 1.8161x; 1.8161x over previous
//
#include <hip/hip_runtime.h>
#include <hip/hip_bf16.h>
#include <math.h>

#define EPSF 1e-8f

constexpr int N_OBJ  = 8192;
constexpr int M_SR   = 4096;
constexpr int N_FACE = 2048;

constexpr int PPB  = 8;              // points per block
constexpr int NBLK = N_OBJ / PPB;    // 1024  (4 blocks/CU -> 16 waves/CU)
constexpr int FT   = 256;            // faces per LDS tile
constexpr int NT   = N_FACE / FT;    // 8

// ws: pensum[1024] floats (fully overwritten each call)

__global__ __launch_bounds__(256) void fused(
    const float* __restrict__ obj, const float* __restrict__ srp,
    const float* __restrict__ verts, const int* __restrict__ faces,
    const float* __restrict__ fnorm, float* __restrict__ out,
    float* __restrict__ pensum)
{
    __shared__ float4 fq[2][4][FT];    // 32 KB component-split (R14: conflict-free)
    __shared__ float  ptd[PPB][8];     // point records
    __shared__ int    scnt[32][9];     // per-(faceSub,point) hit counts (padded)

    const int tid  = threadIdx.x;
    const int w    = tid >> 6;
    const int lane = tid & 63;

    // ---- face tile staging (one face per thread, component-split writes) ----
    auto stage = [&](int buf, int t8) {
        const int f  = t8 * FT + tid;
        const int i0 = faces[3 * f + 0], i1 = faces[3 * f + 1], i2 = faces[3 * f + 2];
        const float ax = verts[3 * i0 + 0], ay = verts[3 * i0 + 1], az = verts[3 * i0 + 2];
        const float bx = verts[3 * i1 + 0], by = verts[3 * i1 + 1], bz = verts[3 * i1 + 2];
        const float cx = verts[3 * i2 + 0], cy = verts[3 * i2 + 1], cz = verts[3 * i2 + 2];
        const float fx = fnorm[3 * f + 0], fy = fnorm[3 * f + 1], fz = fnorm[3 * f + 2];
        const float nf = fx * ax + fy * ay + fz * az;

        const float e0x = bx - ax, e0y = by - ay, e0z = bz - az;
        const float g0x = fy * e0z - fz * e0y, g0y = fz * e0x - fx * e0z, g0z = fx * e0y - fy * e0x;
        const float h0  = g0x * ax + g0y * ay + g0z * az;
        const float e1x = cx - bx, e1y = cy - by, e1z = cz - bz;
        const float g1x = fy * e1z - fz * e1y, g1y = fz * e1x - fx * e1z, g1z = fx * e1y - fy * e1x;
        const float h1  = g1x * bx + g1y * by + g1z * bz;
        const float e2x = ax - cx, e2y = ay - cy, e2z = az - cz;
        const float g2x = fy * e2z - fz * e2y, g2y = fz * e2x - fx * e2z, g2z = fx * e2y - fy * e2x;
        const float h2  = g2x * cx + g2y * cy + g2z * cz;

        fq[buf][0][tid] = make_float4(fx, fy, fz, nf);
        fq[buf][1][tid] = make_float4(g0x, g0y, g0z, h0);
        fq[buf][2][tid] = make_float4(g1x, g1y, g1z, h1);
        fq[buf][3][tid] = make_float4(g2x, g2y, g2z, h2);
    };

    stage(0, 0);    // overlap tile-0 staging with phase A

    // ========== Phase A: NN — 2 points per wave, lane-strided coalesced reads ==========
    {
        const int pA = blockIdx.x * PPB + 2 * w;
        const int pB = pA + 1;
        const float oxA = obj[3 * pA], oyA = obj[3 * pA + 1], ozA = obj[3 * pA + 2];
        const float oxB = obj[3 * pB], oyB = obj[3 * pB + 1], ozB = obj[3 * pB + 2];

        float bestA = 3.4e38f, bestB = 3.4e38f;
        int   biA = 0, biB = 0;
#pragma unroll 4
        for (int j = 0; j < M_SR / 64 - 1; ++j) {
            const int idx = j * 64 + lane;
            float4 v = *(const float4*)(srp + 3 * idx);    // overlapping, dword-aligned
            float dxA = oxA - v.x, dyA = oyA - v.y, dzA = ozA - v.z;
            float dA  = dxA * dxA + dyA * dyA + dzA * dzA;
            if (dA < bestA) { bestA = dA; biA = idx; }
            float dxB = oxB - v.x, dyB = oyB - v.y, dzB = ozB - v.z;
            float dB  = dxB * dxB + dyB * dyB + dzB * dzB;
            if (dB < bestB) { bestB = dB; biB = idx; }
        }
        {   // peeled last group: lane 63 would overrun 4B past srp end
            const int idx = (M_SR / 64 - 1) * 64 + lane;
            float sx = srp[3 * idx], sy = srp[3 * idx + 1], sz = srp[3 * idx + 2];
            float dxA = oxA - sx, dyA = oyA - sy, dzA = ozA - sz;
            float dA  = dxA * dxA + dyA * dyA + dzA * dzA;
            if (dA < bestA) { bestA = dA; biA = idx; }
            float dxB = oxB - sx, dyB = oyB - sy, dzB = ozB - sz;
            float dB  = dxB * dxB + dyB * dyB + dzB * dzB;
            if (dB < bestB) { bestB = dB; biB = idx; }
        }
        for (int off = 1; off < 64; off <<= 1) {
            float od = __shfl_xor(bestA, off); int oi = __shfl_xor(biA, off);
            if (od < bestA || (od == bestA && oi < biA)) { bestA = od; biA = oi; }
            float pd = __shfl_xor(bestB, off); int pi = __shfl_xor(biB, off);
            if (pd < bestB || (pd == bestB && pi < biB)) { bestB = pd; biB = pi; }
        }
        if (lane == 0) {
            float dx = srp[3 * biA] - oxA, dy = srp[3 * biA + 1] - oyA, dz = srp[3 * biA + 2] - ozA;
            ptd[2 * w][0] = oxA; ptd[2 * w][1] = oyA; ptd[2 * w][2] = ozA;
            ptd[2 * w][3] = dx;  ptd[2 * w][4] = dy;  ptd[2 * w][5] = dz;
            ptd[2 * w][6] = bestA;
            out[1 + pA] = 2.0f / (1.0f + expf(100.0f * sqrtf(bestA + EPSF)));

            float ex = srp[3 * biB] - oxB, ey = srp[3 * biB + 1] - oyB, ez = srp[3 * biB + 2] - ozB;
            ptd[2 * w + 1][0] = oxB; ptd[2 * w + 1][1] = oyB; ptd[2 * w + 1][2] = ozB;
            ptd[2 * w + 1][3] = ex;  ptd[2 * w + 1][4] = ey;  ptd[2 * w + 1][5] = ez;
            ptd[2 * w + 1][6] = bestB;
            out[1 + pB] = 2.0f / (1.0f + expf(100.0f * sqrtf(bestB + EPSF)));
        }
    }
    __syncthreads();   // ptd ready, tile-0 staged

    // ========== Phase B: parity — 32 face-subs x 8 points, 8 dbuf tiles ==========
    const int subB = tid >> 3;    // 0..31
    const int ptB  = tid & 7;     // 0..7
    const float ox = ptd[ptB][0], oy = ptd[ptB][1], oz = ptd[ptB][2];
    const float dx = ptd[ptB][3], dy = ptd[ptB][4], dz = ptd[ptB][5];

    int cnt = 0;
    for (int t8 = 0; t8 < NT; ++t8) {
        if (t8 < NT - 1) stage((t8 + 1) & 1, t8 + 1);
        const int buf = t8 & 1;
#pragma unroll 4
        for (int k = 0; k < FT / 32; ++k) {
            const int fl = k * 32 + subB;          // wave reads 128B contiguous: conflict-free
            float4 q0 = fq[buf][0][fl];
            float den = q0.x * dx + q0.y * dy + q0.z * dz;
            float num = q0.w - (q0.x * ox + q0.y * oy + q0.z * oz);
            float Px  = den * ox + num * dx;
            float Py  = den * oy + num * dy;
            float Pz  = den * oz + num * dz;
            bool pos = den >= 0.0f;

            float4 q1 = fq[buf][1][fl];
            bool ok0 = ((q1.x * Px + q1.y * Py + q1.z * Pz - den * q1.w) >= 0.0f) == pos;
            float4 q2 = fq[buf][2][fl];
            bool ok1 = ((q2.x * Px + q2.y * Py + q2.z * Pz - den * q2.w) >= 0.0f) == pos;
            float4 q3 = fq[buf][3][fl];
            bool ok2 = ((q3.x * Px + q3.y * Py + q3.z * Pz - den * q3.w) >= 0.0f) == pos;

            bool tok = (num >= 0.0f) == pos;
            bool aok = fabsf(den) >= EPSF;
            cnt += (ok0 & ok1 & ok2 & tok & aok) ? 1 : 0;
        }
        __syncthreads();
    }

    // ========== Phase C: in-block parity + pen partial ==========
    scnt[subB][ptB] = cnt;
    __syncthreads();
    float s = 0.0f;
    if (tid < PPB) {
        int tot = 0;
#pragma unroll
        for (int sb = 0; sb < 32; ++sb) tot += scnt[sb][tid];
        s = (tot & 1) ? ptd[tid][6] : 0.0f;
    }
#pragma unroll
    for (int off = 1; off < 8; off <<= 1) s += __shfl_xor(s, off);
    if (tid == 0) pensum[blockIdx.x] = s;
}

// ================= FIN: sum 1024 partials -> sqrt -> out[0] =================
__global__ __launch_bounds__(256) void fin(
    const float* __restrict__ pensum, float* __restrict__ out)
{
    __shared__ float wsum[4];
    const int t = threadIdx.x;
    float4 v = ((const float4*)pensum)[t];
    float s = v.x + v.y + v.z + v.w;
#pragma unroll
    for (int off = 1; off < 64; off <<= 1) s += __shfl_xor(s, off);
    if ((t & 63) == 0) wsum[t >> 6] = s;
    __syncthreads();
    if (t == 0) out[0] = sqrtf(wsum[0] + wsum[1] + wsum[2] + wsum[3]);
}

extern "C" void kernel_launch(void* const* d_in, const int* in_sizes, int n_in,
                              void* d_out, int out_size, void* d_ws, size_t ws_size,
                              hipStream_t stream)
{
    const float* obj   = (const float*)d_in[0];
    const float* srp   = (const float*)d_in[1];
    const float* verts = (const float*)d_in[2];
    const int*   faces = (const int*)d_in[3];
    const float* fnorm = (const float*)d_in[4];
    float*       out   = (float*)d_out;
    float*       pensum = (float*)d_ws;

    fused<<<NBLK, 256, 0, stream>>>(obj, srp, verts, faces, fnorm, out, pensum);
    fin<<<1, 256, 0, stream>>>(pensum, out);
}